// Round 1
// baseline (390.597 us; speedup 1.0000x reference)
//
#include <hip/hip_runtime.h>

#define D_IN 256
#define D_OUT 1024
#define STACK 4
#define BATCH 65536

// FWHT over 256 elements distributed as: lane l (of 64) holds elements
// e = 4*l + j, j=0..3. Bits 0-1 of e are in-lane, bits 2-7 are lane bits.
__device__ __forceinline__ void fwht256(float v[4], int lane) {
    // bit 0: pairs (0,1),(2,3)
    float a0 = v[0] + v[1];
    float a1 = v[0] - v[1];
    float a2 = v[2] + v[3];
    float a3 = v[2] - v[3];
    // bit 1: pairs (0,2),(1,3)
    v[0] = a0 + a2;
    v[2] = a0 - a2;
    v[1] = a1 + a3;
    v[3] = a1 - a3;
    // bits 2..7: cross-lane butterflies, distances 1,2,4,8,16,32
#pragma unroll
    for (int d = 1; d < 64; d <<= 1) {
        const bool upper = (lane & d) != 0;
#pragma unroll
        for (int j = 0; j < 4; ++j) {
            float o = __shfl_xor(v[j], d, 64);
            v[j] = upper ? (o - v[j]) : (v[j] + o);
        }
    }
}

__global__ __launch_bounds__(256) void whvi_fwht_kernel(
    const float* __restrict__ x,
    const float* __restrict__ s1,
    const float* __restrict__ s2,
    const float* __restrict__ g_mu,
    const float* __restrict__ g_rho,
    const float* __restrict__ eps,
    float* __restrict__ out,
    int nrows)
{
    const int lane = threadIdx.x & 63;
    const int waveInBlock = threadIdx.x >> 6;
    const int wavesPerBlock = blockDim.x >> 6;
    const int gwave = blockIdx.x * wavesPerBlock + waveInBlock;
    const int nwaves = gridDim.x * wavesPerBlock;

    const int e0 = lane << 2;   // this lane's element base within a 256-segment

    // Hoist per-lane scale constants into registers (16 KB total across arrays,
    // loaded once per wave; L2-resident).
    float s1v[STACK][4], s2v[STACK][4], gv[STACK][4];
#pragma unroll
    for (int k = 0; k < STACK; ++k) {
        const float4 a = *reinterpret_cast<const float4*>(s1   + k * D_IN + e0);
        const float4 b = *reinterpret_cast<const float4*>(s2   + k * D_IN + e0);
        const float4 m = *reinterpret_cast<const float4*>(g_mu + k * D_IN + e0);
        const float4 r = *reinterpret_cast<const float4*>(g_rho + k * D_IN + e0);
        const float4 e = *reinterpret_cast<const float4*>(eps  + k * D_IN + e0);
        s1v[k][0] = a.x; s1v[k][1] = a.y; s1v[k][2] = a.z; s1v[k][3] = a.w;
        s2v[k][0] = b.x; s2v[k][1] = b.y; s2v[k][2] = b.z; s2v[k][3] = b.w;
        // g = g_mu + softplus(g_rho) * epsilon
        gv[k][0] = m.x + log1pf(expf(r.x)) * e.x;
        gv[k][1] = m.y + log1pf(expf(r.y)) * e.y;
        gv[k][2] = m.z + log1pf(expf(r.z)) * e.z;
        gv[k][3] = m.w + log1pf(expf(r.w)) * e.w;
    }

    for (int row = gwave; row < nrows; row += nwaves) {
        const float4 xi = *reinterpret_cast<const float4*>(x + (size_t)row * D_IN + e0);
        float xr[4] = {xi.x, xi.y, xi.z, xi.w};

#pragma unroll
        for (int k = 0; k < STACK; ++k) {
            float v[4];
#pragma unroll
            for (int j = 0; j < 4; ++j) v[j] = xr[j] * s2v[k][j];
            fwht256(v, lane);
#pragma unroll
            for (int j = 0; j < 4; ++j) v[j] *= gv[k][j];
            fwht256(v, lane);
            float4 o;
            o.x = v[0] * s1v[k][0];
            o.y = v[1] * s1v[k][1];
            o.z = v[2] * s1v[k][2];
            o.w = v[3] * s1v[k][3];
            *reinterpret_cast<float4*>(out + (size_t)row * D_OUT + k * D_IN + e0) = o;
        }
    }
}

extern "C" void kernel_launch(void* const* d_in, const int* in_sizes, int n_in,
                              void* d_out, int out_size, void* d_ws, size_t ws_size,
                              hipStream_t stream) {
    const float* x     = (const float*)d_in[0];
    const float* s1    = (const float*)d_in[1];
    const float* s2    = (const float*)d_in[2];
    const float* g_mu  = (const float*)d_in[3];
    const float* g_rho = (const float*)d_in[4];
    const float* eps   = (const float*)d_in[5];
    float* out = (float*)d_out;

    const int nrows = in_sizes[0] / D_IN;   // 65536
    const int block = 256;                  // 4 waves
    const int grid  = 2048;                 // 8 blocks/CU, 8 rows per wave
    whvi_fwht_kernel<<<grid, block, 0, stream>>>(x, s1, s2, g_mu, g_rho, eps,
                                                 out, nrows);
}

// Round 2
// 343.358 us; speedup vs baseline: 1.1376x; 1.1376x over previous
//
#include <hip/hip_runtime.h>

#define D_IN 256
#define D_OUT 1024
#define STACK 4

typedef unsigned u2 __attribute__((ext_vector_type(2)));

// DPP move: copy v with a quad_perm lane permutation (pure VALU, no DS pipe).
template <int CTRL>
__device__ __forceinline__ float dppmov(float v) {
    int iv = __float_as_int(v);
    return __int_as_float(__builtin_amdgcn_update_dpp(iv, iv, CTRL, 0xF, 0xF, false));
}

// ds_swizzle with immediate XOR pattern (BitMode: xor<<10 | and 0x1F).
template <int PAT>
__device__ __forceinline__ float swz(float v) {
    return __int_as_float(__builtin_amdgcn_ds_swizzle(__float_as_int(v), PAT));
}

// FWHT over 256 elements: lane l holds elements 4l..4l+3.
// Element bits 0-1 in-lane; element distances 4..128 = lane-xor 1..32.
// Butterfly: lower' = v + o ; upper' = o - v  ==>  v' = fma(sgn, v, o),
// sgn = -1 iff this lane is the upper partner of the stage.
__device__ __forceinline__ void fwht256(float v[4], const float sg[6]) {
    // element bit 0: (0,1),(2,3)
    float a0 = v[0] + v[1];
    float a1 = v[0] - v[1];
    float a2 = v[2] + v[3];
    float a3 = v[2] - v[3];
    // element bit 1: (0,2),(1,3)
    v[0] = a0 + a2;
    v[2] = a0 - a2;
    v[1] = a1 + a3;
    v[3] = a1 - a3;

    // lane-xor 1: quad_perm [1,0,3,2] = 0xB1
#pragma unroll
    for (int j = 0; j < 4; ++j)
        v[j] = __builtin_fmaf(sg[0], v[j], dppmov<0xB1>(v[j]));
    // lane-xor 2: quad_perm [2,3,0,1] = 0x4E
#pragma unroll
    for (int j = 0; j < 4; ++j)
        v[j] = __builtin_fmaf(sg[1], v[j], dppmov<0x4E>(v[j]));
    // lane-xor 4: ds_swizzle xor=4 -> (4<<10)|0x1F = 0x101F
#pragma unroll
    for (int j = 0; j < 4; ++j)
        v[j] = __builtin_fmaf(sg[2], v[j], swz<0x101F>(v[j]));
    // lane-xor 8: ds_swizzle xor=8 -> 0x201F
#pragma unroll
    for (int j = 0; j < 4; ++j)
        v[j] = __builtin_fmaf(sg[3], v[j], swz<0x201F>(v[j]));

    // lane-xor 16: v_permlane16_swap_b32. With both inputs = v:
    // r[0] = A (even-16 dup), r[1] = B (odd-16 dup); v' = fma(sgn, B, A).
#pragma unroll
    for (int j = 0; j < 4; ++j) {
#if __has_builtin(__builtin_amdgcn_permlane16_swap)
        u2 r = __builtin_amdgcn_permlane16_swap(__float_as_uint(v[j]),
                                                __float_as_uint(v[j]), false, false);
        v[j] = __builtin_fmaf(sg[4], __uint_as_float(r[1]), __uint_as_float(r[0]));
#else
        v[j] = __builtin_fmaf(sg[4], v[j], swz<0x401F>(v[j]));
#endif
    }

    // lane-xor 32: v_permlane32_swap_b32 (same both-halves trick).
#pragma unroll
    for (int j = 0; j < 4; ++j) {
        u2 r = __builtin_amdgcn_permlane32_swap(__float_as_uint(v[j]),
                                                __float_as_uint(v[j]), false, false);
        v[j] = __builtin_fmaf(sg[5], __uint_as_float(r[1]), __uint_as_float(r[0]));
    }
}

__global__ __launch_bounds__(256) void whvi_fwht_kernel(
    const float* __restrict__ x,
    const float* __restrict__ s1,
    const float* __restrict__ s2,
    const float* __restrict__ g_mu,
    const float* __restrict__ g_rho,
    const float* __restrict__ eps,
    float* __restrict__ out,
    int nrows)
{
    const int lane = threadIdx.x & 63;
    const int waveInBlock = threadIdx.x >> 6;
    const int wavesPerBlock = blockDim.x >> 6;
    const int gwave = blockIdx.x * wavesPerBlock + waveInBlock;
    const int nwaves = gridDim.x * wavesPerBlock;

    const int e0 = lane << 2;  // this lane's element base within a 256-segment

    // Per-stage butterfly signs: -1 iff lane is the upper partner.
    float sg[6];
#pragma unroll
    for (int i = 0; i < 6; ++i)
        sg[i] = (lane & (1 << i)) ? -1.0f : 1.0f;

    // Hoist per-lane scale constants into registers (48 VGPRs).
    float s1v[STACK][4], s2v[STACK][4], gv[STACK][4];
#pragma unroll
    for (int k = 0; k < STACK; ++k) {
        const float4 a = *reinterpret_cast<const float4*>(s1    + k * D_IN + e0);
        const float4 b = *reinterpret_cast<const float4*>(s2    + k * D_IN + e0);
        const float4 m = *reinterpret_cast<const float4*>(g_mu  + k * D_IN + e0);
        const float4 r = *reinterpret_cast<const float4*>(g_rho + k * D_IN + e0);
        const float4 e = *reinterpret_cast<const float4*>(eps   + k * D_IN + e0);
        s1v[k][0] = a.x; s1v[k][1] = a.y; s1v[k][2] = a.z; s1v[k][3] = a.w;
        s2v[k][0] = b.x; s2v[k][1] = b.y; s2v[k][2] = b.z; s2v[k][3] = b.w;
        // g = g_mu + softplus(g_rho) * epsilon
        gv[k][0] = m.x + log1pf(expf(r.x)) * e.x;
        gv[k][1] = m.y + log1pf(expf(r.y)) * e.y;
        gv[k][2] = m.z + log1pf(expf(r.z)) * e.z;
        gv[k][3] = m.w + log1pf(expf(r.w)) * e.w;
    }

    for (int row = gwave; row < nrows; row += nwaves) {
        const float4 xi = *reinterpret_cast<const float4*>(x + (size_t)row * D_IN + e0);
        float xr[4] = {xi.x, xi.y, xi.z, xi.w};

#pragma unroll
        for (int k = 0; k < STACK; ++k) {
            float v[4];
#pragma unroll
            for (int j = 0; j < 4; ++j) v[j] = xr[j] * s2v[k][j];
            fwht256(v, sg);
#pragma unroll
            for (int j = 0; j < 4; ++j) v[j] *= gv[k][j];
            fwht256(v, sg);
            float4 o;
            o.x = v[0] * s1v[k][0];
            o.y = v[1] * s1v[k][1];
            o.z = v[2] * s1v[k][2];
            o.w = v[3] * s1v[k][3];
            *reinterpret_cast<float4*>(out + (size_t)row * D_OUT + k * D_IN + e0) = o;
        }
    }
}

extern "C" void kernel_launch(void* const* d_in, const int* in_sizes, int n_in,
                              void* d_out, int out_size, void* d_ws, size_t ws_size,
                              hipStream_t stream) {
    const float* x     = (const float*)d_in[0];
    const float* s1    = (const float*)d_in[1];
    const float* s2    = (const float*)d_in[2];
    const float* g_mu  = (const float*)d_in[3];
    const float* g_rho = (const float*)d_in[4];
    const float* eps   = (const float*)d_in[5];
    float* out = (float*)d_out;

    const int nrows = in_sizes[0] / D_IN;   // 65536
    const int block = 256;                  // 4 waves
    const int grid  = 2048;                 // 8 rows per wave, grid-stride
    whvi_fwht_kernel<<<grid, block, 0, stream>>>(x, s1, s2, g_mu, g_rho, eps,
                                                 out, nrows);
}